// Round 1
// baseline (595.000 us; speedup 1.0000x reference)
//
#include <hip/hip_runtime.h>

// Output: diag(ics_mask - params * r_mask), an N x N float32 matrix.
// N = 12288. Pure streaming-write problem (~604 MB out per call; harness
// poisons d_out to 0xAA before every timed launch, so we must write it all).

#define DIAG_N 12288
#define DIAG_N4 (DIAG_N / 4)   // 3072 float4s per row; N % 4 == 0 so a
                               // float4 never straddles a row boundary.

__global__ __launch_bounds__(256) void diag_fill_kernel(
    const float* __restrict__ params,
    const int*   __restrict__ r_mask,
    const int*   __restrict__ ics_mask,
    float4*      __restrict__ out)
{
    const int total4 = DIAG_N * DIAG_N4;              // 37,748,736 < 2^31
    const int stride = gridDim.x * blockDim.x;
    for (int idx = blockIdx.x * blockDim.x + threadIdx.x;
         idx < total4; idx += stride) {
        const int row = idx / DIAG_N4;                // magic-mul div by 3072
        const int rem = idx - row * DIAG_N4;
        float4 v = make_float4(0.f, 0.f, 0.f, 0.f);
        // The diagonal element of this row (column == row) lives in the
        // float4 with rem == row>>2, at lane row&3.
        if (rem == (row >> 2)) {
            const float d = (float)ics_mask[row]
                          - params[row] * (float)r_mask[row];
            const int lane = row & 3;
            v.x = (lane == 0) ? d : 0.f;
            v.y = (lane == 1) ? d : 0.f;
            v.z = (lane == 2) ? d : 0.f;
            v.w = (lane == 3) ? d : 0.f;
        }
        out[idx] = v;
    }
}

extern "C" void kernel_launch(void* const* d_in, const int* in_sizes, int n_in,
                              void* d_out, int out_size, void* d_ws, size_t ws_size,
                              hipStream_t stream) {
    const float* params   = (const float*)d_in[0];
    const int*   r_mask   = (const int*)d_in[1];
    const int*   ics_mask = (const int*)d_in[2];
    float4*      out      = (float4*)d_out;

    // 2048 blocks x 256 threads: 524,288 threads, ~72 float4 stores each.
    // Saturates HBM write BW; grid-stride covers the whole matrix.
    dim3 grid(2048), block(256);
    hipLaunchKernelGGL(diag_fill_kernel, grid, block, 0, stream,
                       params, r_mask, ics_mask, out);
}

// Round 2
// 572.427 us; speedup vs baseline: 1.0394x; 1.0394x over previous
//
#include <hip/hip_runtime.h>

// Output: diag(ics_mask - params * r_mask), an N x N float32 matrix, N=12288.
// ~604 MB of output re-poisoned to 0xAA before every timed launch -> the job
// is a max-bandwidth zero-fill plus 12288 diagonal scatter writes.
//
// Round-1 lesson: my hand-rolled grid-stride fill ran ~1 TB/s effective while
// the harness's own rocclr fillBufferAligned sustains 6.28 TB/s on the same
// buffer. So delegate the fill to hipMemsetAsync (graph-capturable, harness
// uses it itself) and only scatter the diagonal in a tiny kernel.

#define DIAG_N 12288

__global__ __launch_bounds__(256) void diag_scatter_kernel(
    const float* __restrict__ params,
    const int*   __restrict__ r_mask,
    const int*   __restrict__ ics_mask,
    float*       __restrict__ out)
{
    const int i = blockIdx.x * blockDim.x + threadIdx.x;
    if (i < DIAG_N) {
        const float d = (float)ics_mask[i] - params[i] * (float)r_mask[i];
        out[(size_t)i * (DIAG_N + 1)] = d;   // element (i, i)
    }
}

extern "C" void kernel_launch(void* const* d_in, const int* in_sizes, int n_in,
                              void* d_out, int out_size, void* d_ws, size_t ws_size,
                              hipStream_t stream) {
    const float* params   = (const float*)d_in[0];
    const int*   r_mask   = (const int*)d_in[1];
    const int*   ics_mask = (const int*)d_in[2];
    float*       out      = (float*)d_out;

    // Phase 1: zero the whole matrix at fillBuffer speed (~6.3 TB/s measured
    // on this very buffer by the harness's poison pass).
    hipMemsetAsync(d_out, 0, (size_t)out_size * sizeof(float), stream);

    // Phase 2: write the 12288 diagonal elements (ordered after the memset on
    // the same stream).
    dim3 grid((DIAG_N + 255) / 256), block(256);
    hipLaunchKernelGGL(diag_scatter_kernel, grid, block, 0, stream,
                       params, r_mask, ics_mask, out);
}